// Round 11
// baseline (61.228 us; speedup 1.0000x reference)
//
#include <hip/hip_runtime.h>

#define NB 4
#define NC 128
#define NH 128
#define NW 128
#define EPSV 0.2f
#define TH 2

typedef float v4f __attribute__((ext_vector_type(4)));
typedef float v2f __attribute__((ext_vector_type(2)));

// Fused kernel (R10 skeleton). 256 blocks = (b, h-pair), XCD-swizzled, 512 thr.
// Phase A: channel means via float4 loads (R10, unchanged).
// Phase B: 9-tap softmax weights -> LDS (unchanged).
// Phase C: R11 change — x loads NONTEMPORAL (keep L2 clean for writes),
//          output stores PLAIN write-back (fill-kernel path, 6.9 TB/s).
__global__ __launch_bounds__(512) void fused_carafe(const float* __restrict__ x,
                                                    float* __restrict__ out) {
    const int chunk = gridDim.x >> 3;            // 32
    const int bid = blockIdx.x;
    const int swz = (bid & 7) * chunk + (bid >> 3);
    const int b  = swz >> 6;
    const int h0 = (swz & 63) * TH;

    __shared__ v4f  partA[4][4][32];             // 8 KB [row][cgrp][w4]
    __shared__ float mrow[4][NW];                // 2 KB
    __shared__ float wgt[TH][9][NW];             // 9 KB

    const int tid = threadIdx.x;

    // ---------------- Phase A: channel means, float4 ----------------
    {
        const int r  = tid >> 7;                 // 0..3 -> row h0-1+r
        const int cg = (tid >> 5) & 3;           // 0..3 -> 32 channels
        const int w4 = tid & 31;                 // float4 position
        const int hh = h0 - 1 + r;
        v4f s = {0.f, 0.f, 0.f, 0.f};
        if (hh >= 0 && hh < NH) {
            const v4f* px = (const v4f*)(x + (((size_t)(b * NC + cg * 32)) * NH + hh) * NW) + w4;
            v4f s0 = {0.f,0.f,0.f,0.f}, s1 = {0.f,0.f,0.f,0.f};
            #pragma unroll 8
            for (int c = 0; c < 32; c += 2) {
                s0 += px[(size_t)c * (NH * NW / 4)];
                s1 += px[(size_t)(c + 1) * (NH * NW / 4)];
            }
            s = s0 + s1;
        }
        partA[r][cg][w4] = s;
    }
    __syncthreads();
    if (tid < 128) {
        const int r  = tid >> 5;                 // 0..3
        const int w4 = tid & 31;
        v4f s = partA[r][0][w4] + partA[r][1][w4] + partA[r][2][w4] + partA[r][3][w4];
        s *= (1.0f / NC);
        *(v4f*)&mrow[r][4 * w4] = s;
    }
    __syncthreads();

    // ---------------- Phase B: softmax weights ----------------
    if (tid < 256) {
        const int r = tid >> 7;                  // source row h0+r
        const int w = tid & 127;
        const float mc = mrow[r + 1][w];
        float v[9];
        float vmax = -1e30f;
        #pragma unroll
        for (int ky = 0; ky < 3; ++ky) {
            #pragma unroll
            for (int kx = -1; kx <= 1; ++kx) {
                const int ww = w + kx;
                const float mp = (ww >= 0 && ww < NW) ? mrow[r + ky][ww] : 0.f;
                const float g = mp - mc;
                const float val = 1.0f / (g * g + EPSV);
                v[ky * 3 + kx + 1] = val;
                vmax = fmaxf(vmax, val);
            }
        }
        float sum = 0.f;
        #pragma unroll
        for (int k = 0; k < 9; ++k) { v[k] = __expf(v[k] - vmax); sum += v[k]; }
        const float rs = 1.0f / sum;
        #pragma unroll
        for (int k = 0; k < 9; ++k) wgt[r][k][w] = v[k] * rs;
    }
    __syncthreads();

    // ---------------- Phase C: reassembly ----------------
    const int wp = tid & 63;                     // source cols 2wp, 2wp+1
    const int cg_ = tid >> 6;                    // 0..7 -> 16 channels each
    const int wa = 2 * wp;

    float wA0[9], wB0[9], wA1[9], wB1[9];
    #pragma unroll
    for (int k = 0; k < 9; ++k) {
        wA0[k] = wgt[0][k][wa];  wB0[k] = wgt[0][k][wa + 1];
        wA1[k] = wgt[1][k][wa];  wB1[k] = wgt[1][k][wa + 1];
    }

    const bool rv0 = (h0 > 0), rv3 = (h0 + 2 < NH);
    const bool tv0 = (wp > 0), tv3 = (wp < 63);

    #pragma unroll 2
    for (int i = 0; i < 16; ++i) {
        const int c = cg_ * 16 + i;
        const float* xc = x + ((size_t)(b * NC + c)) * (NH * NW);

        float a[4][4];                           // rows h0-1..h0+2, taps wa-1..wa+2
        #pragma unroll
        for (int rr = 0; rr < 4; ++rr) {
            const int hh = h0 - 1 + rr;
            const bool rv = (rr == 0) ? rv0 : ((rr == 3) ? rv3 : true);
            const float* row = xc + hh * NW + wa;
            const v2f m = rv ? __builtin_nontemporal_load((const v2f*)row)
                             : (v2f){0.f, 0.f};
            a[rr][0] = (rv && tv0) ? __builtin_nontemporal_load(row - 1) : 0.f;
            a[rr][1] = m.x;
            a[rr][2] = m.y;
            a[rr][3] = (rv && tv3) ? __builtin_nontemporal_load(row + 2) : 0.f;
        }

        float v0a = 0.f, v0b = 0.f, v1a = 0.f, v1b = 0.f;
        #pragma unroll
        for (int ky = 0; ky < 3; ++ky) {
            #pragma unroll
            for (int kx = 0; kx < 3; ++kx) {
                const int k = ky * 3 + kx;
                v0a += wA0[k] * a[ky][kx];
                v0b += wB0[k] * a[ky][kx + 1];
                v1a += wA1[k] * a[ky + 1][kx];
                v1b += wB1[k] * a[ky + 1][kx + 1];
            }
        }

        float* o = out + ((size_t)(b * NC + c) * (NH * 2) + 2 * h0) * (NW * 2) + 4 * wp;
        const v4f p0 = {v0a, v0a, v0b, v0b};
        const v4f p1 = {v1a, v1a, v1b, v1b};
        *(v4f*)(o)                = p0;
        *(v4f*)(o + (NW * 2))     = p0;
        *(v4f*)(o + 2 * (NW * 2)) = p1;
        *(v4f*)(o + 3 * (NW * 2)) = p1;
    }
}

extern "C" void kernel_launch(void* const* d_in, const int* in_sizes, int n_in,
                              void* d_out, int out_size, void* d_ws, size_t ws_size,
                              hipStream_t stream) {
    const float* x = (const float*)d_in[0];
    float* out = (float*)d_out;
    fused_carafe<<<dim3(NB * NH / TH), dim3(512), 0, stream>>>(x, out);
}

// Round 12
// 36.524 us; speedup vs baseline: 1.6764x; 1.6764x over previous
//
#include <hip/hip_runtime.h>

#define NB 4
#define NC 128
#define NH 128
#define NW 128
#define EPSV 0.2f
#define TH 2

typedef float v4f __attribute__((ext_vector_type(4)));
typedef float v2f __attribute__((ext_vector_type(2)));

// R12: w-split for 2 blocks/CU phase overlap.
// 512 blocks = (b, h-pair, w-half), XCD-swizzled, 256 thr each.
// Per block: 2 source rows x 64 w columns.
// Phase A: channel means of rows h0-1..h0+2 over own w-half (+1 float4 halo
//          col), float4 loads; 4-way LDS reduce.
// Phase B: 9-tap softmax weights for 2 rows x 64 w -> LDS.
// Phase C: reassembly; 16B nontemporal stores (NT-store+plain-load = proven
//          best combo, R10/R11 A/B).
__global__ __launch_bounds__(256) void fused_carafe(const float* __restrict__ x,
                                                    float* __restrict__ out) {
    const int chunk = gridDim.x >> 3;            // 64
    const int bid = blockIdx.x;
    const int swz = (bid & 7) * chunk + (bid >> 3);
    const int b   = swz >> 7;                    // 128 blocks per batch
    const int rem = swz & 127;
    const int h0  = (rem >> 1) * TH;
    const int hw  = rem & 1;                     // w-half: cols [64hw, 64hw+64)

    // local float-col index L = w_global - 60*hw, valid range [0, 68)
    __shared__ v4f  partA[4][4][17];             // 4.25 KB [row][cgrp][p]
    __shared__ float mrow[4][68];                // mean rows h0-1..h0+2
    __shared__ float wgt[TH][9][64];             // 4.5 KB

    const int tid = threadIdx.x;

    // ---------------- Phase A: channel means, float4 ----------------
    {
        const int r  = tid >> 6;                 // 0..3 -> row h0-1+r
        const int cg = (tid >> 4) & 3;           // 0..3 -> 32 channels
        const int t  = tid & 15;                 // float4 position p = t
        const int hh = h0 - 1 + r;
        const int w4base = 15 * hw;              // float4 cols [15hw, 15hw+17)
        v4f s = {0.f, 0.f, 0.f, 0.f};
        v4f s2 = {0.f, 0.f, 0.f, 0.f};
        if (hh >= 0 && hh < NH) {
            const v4f* px = (const v4f*)(x + (((size_t)(b * NC + cg * 32)) * NH + hh) * NW);
            #pragma unroll 8
            for (int c = 0; c < 32; ++c)
                s += px[(size_t)c * (NH * NW / 4) + w4base + t];
            if (t == 0) {                        // 17th position
                #pragma unroll 8
                for (int c = 0; c < 32; ++c)
                    s2 += px[(size_t)c * (NH * NW / 4) + w4base + 16];
            }
        }
        partA[r][cg][t] = s;
        if (t == 0) partA[r][cg][16] = s2;
    }
    __syncthreads();
    if (tid < 68) {
        const int r = tid / 17;
        const int p = tid % 17;
        v4f s = partA[r][0][p] + partA[r][1][p] + partA[r][2][p] + partA[r][3][p];
        s *= (1.0f / NC);
        *(v4f*)&mrow[r][4 * p] = s;
    }
    __syncthreads();

    // ---------------- Phase B: softmax weights ----------------
    if (tid < 128) {
        const int r  = tid >> 6;                 // source row h0+r
        const int wl = tid & 63;                 // local col
        const int wg = 64 * hw + wl;             // global col
        const int lc = wl + 4 * hw;              // mrow local center
        const float mc = mrow[r + 1][lc];
        float v[9];
        float vmax = -1e30f;
        #pragma unroll
        for (int ky = 0; ky < 3; ++ky) {
            #pragma unroll
            for (int kx = -1; kx <= 1; ++kx) {
                const int wwg = wg + kx;
                const int lw  = lc + kx;
                const int lwc = lw < 0 ? 0 : (lw > 67 ? 67 : lw);
                const float mp = (wwg >= 0 && wwg < NW) ? mrow[r + ky][lwc] : 0.f;
                const float g = mp - mc;
                const float val = 1.0f / (g * g + EPSV);
                v[ky * 3 + kx + 1] = val;
                vmax = fmaxf(vmax, val);
            }
        }
        float sum = 0.f;
        #pragma unroll
        for (int k = 0; k < 9; ++k) { v[k] = __expf(v[k] - vmax); sum += v[k]; }
        const float rs = 1.0f / sum;
        #pragma unroll
        for (int k = 0; k < 9; ++k) wgt[r][k][wl] = v[k] * rs;
    }
    __syncthreads();

    // ---------------- Phase C: reassembly ----------------
    const int wpl = tid & 31;                    // local w-pair
    const int cg_ = tid >> 5;                    // 0..7 -> 16 channels each
    const int wl  = 2 * wpl;                     // local col of pair
    const int wa  = 64 * hw + wl;                // global col of pair

    float wA0[9], wB0[9], wA1[9], wB1[9];
    #pragma unroll
    for (int k = 0; k < 9; ++k) {
        wA0[k] = wgt[0][k][wl];  wB0[k] = wgt[0][k][wl + 1];
        wA1[k] = wgt[1][k][wl];  wB1[k] = wgt[1][k][wl + 1];
    }

    const bool rv0 = (h0 > 0), rv3 = (h0 + 2 < NH);
    const bool tv0 = (wa > 0), tv3 = (wa + 2 < NW);

    #pragma unroll 2
    for (int i = 0; i < 16; ++i) {
        const int c = cg_ * 16 + i;
        const float* xc = x + ((size_t)(b * NC + c)) * (NH * NW);

        float a[4][4];                           // rows h0-1..h0+2, taps wa-1..wa+2
        #pragma unroll
        for (int rr = 0; rr < 4; ++rr) {
            const int hh = h0 - 1 + rr;
            const bool rv = (rr == 0) ? rv0 : ((rr == 3) ? rv3 : true);
            const float* row = xc + hh * NW + wa;
            const v2f m = rv ? *(const v2f*)row : (v2f){0.f, 0.f};
            a[rr][0] = (rv && tv0) ? row[-1] : 0.f;
            a[rr][1] = m.x;
            a[rr][2] = m.y;
            a[rr][3] = (rv && tv3) ? row[2] : 0.f;
        }

        float v0a = 0.f, v0b = 0.f, v1a = 0.f, v1b = 0.f;
        #pragma unroll
        for (int ky = 0; ky < 3; ++ky) {
            #pragma unroll
            for (int kx = 0; kx < 3; ++kx) {
                const int k = ky * 3 + kx;
                v0a += wA0[k] * a[ky][kx];
                v0b += wB0[k] * a[ky][kx + 1];
                v1a += wA1[k] * a[ky + 1][kx];
                v1b += wB1[k] * a[ky + 1][kx + 1];
            }
        }

        float* o = out + ((size_t)(b * NC + c) * (NH * 2) + 2 * h0) * (NW * 2)
                       + 128 * hw + 4 * wpl;
        const v4f p0 = {v0a, v0a, v0b, v0b};
        const v4f p1 = {v1a, v1a, v1b, v1b};
        __builtin_nontemporal_store(p0, (v4f*)(o));
        __builtin_nontemporal_store(p0, (v4f*)(o + (NW * 2)));
        __builtin_nontemporal_store(p1, (v4f*)(o + 2 * (NW * 2)));
        __builtin_nontemporal_store(p1, (v4f*)(o + 3 * (NW * 2)));
    }
}

extern "C" void kernel_launch(void* const* d_in, const int* in_sizes, int n_in,
                              void* d_out, int out_size, void* d_ws, size_t ws_size,
                              hipStream_t stream) {
    const float* x = (const float*)d_in[0];
    float* out = (float*)d_out;
    fused_carafe<<<dim3(NB * NH / TH * 2), dim3(256), 0, stream>>>(x, out);
}

// Round 13
// 33.296 us; speedup vs baseline: 1.8389x; 1.0970x over previous
//
#include <hip/hip_runtime.h>

#define NB 4
#define NC 128
#define NH 128
#define NW 128
#define EPSV 0.2f
#define TH 2

typedef float v4f __attribute__((ext_vector_type(4)));
typedef float v2f __attribute__((ext_vector_type(2)));

// R13 = R10 structure at 1024 threads/block (16 waves/CU) for deeper
// store-queue occupancy during phase C. Grid 256 = (b, h-pair), swizzled.
// Phase A: channel means rows h0-1..h0+2, float4 loads, 8-way LDS reduce.
// Phase B: 9-tap softmax weights -> LDS (identical math).
// Phase C: reassembly; plain loads (L2-warm from A) + 16B NT stores
//          (NT-store+plain-load = proven best, R10/R11 A/B).
__global__ __launch_bounds__(1024) void fused_carafe(const float* __restrict__ x,
                                                     float* __restrict__ out) {
    const int chunk = gridDim.x >> 3;            // 32
    const int bid = blockIdx.x;
    const int swz = (bid & 7) * chunk + (bid >> 3);
    const int b  = swz >> 6;
    const int h0 = (swz & 63) * TH;

    __shared__ v4f  partA[4][8][32];             // 16 KB [row][cgrp][w4]
    __shared__ float mrow[4][NW];                // 2 KB
    __shared__ float wgt[TH][9][NW];             // 9 KB

    const int tid = threadIdx.x;

    // ---------------- Phase A: channel means, float4 ----------------
    {
        const int r  = tid >> 8;                 // 0..3 -> row h0-1+r
        const int cg = (tid >> 5) & 7;           // 0..7 -> 16 channels
        const int w4 = tid & 31;                 // float4 position
        const int hh = h0 - 1 + r;
        v4f s = {0.f, 0.f, 0.f, 0.f};
        if (hh >= 0 && hh < NH) {
            const v4f* px = (const v4f*)(x + (((size_t)(b * NC + cg * 16)) * NH + hh) * NW) + w4;
            v4f s0 = {0.f,0.f,0.f,0.f}, s1 = {0.f,0.f,0.f,0.f};
            #pragma unroll 8
            for (int c = 0; c < 16; c += 2) {
                s0 += px[(size_t)c * (NH * NW / 4)];
                s1 += px[(size_t)(c + 1) * (NH * NW / 4)];
            }
            s = s0 + s1;
        }
        partA[r][cg][w4] = s;
    }
    __syncthreads();
    if (tid < 128) {
        const int r  = tid >> 5;                 // 0..3
        const int w4 = tid & 31;
        v4f s = partA[r][0][w4];
        #pragma unroll
        for (int g = 1; g < 8; ++g) s += partA[r][g][w4];
        s *= (1.0f / NC);
        *(v4f*)&mrow[r][4 * w4] = s;
    }
    __syncthreads();

    // ---------------- Phase B: softmax weights ----------------
    if (tid < 256) {
        const int r = tid >> 7;                  // source row h0+r
        const int w = tid & 127;
        const float mc = mrow[r + 1][w];
        float v[9];
        float vmax = -1e30f;
        #pragma unroll
        for (int ky = 0; ky < 3; ++ky) {
            #pragma unroll
            for (int kx = -1; kx <= 1; ++kx) {
                const int ww = w + kx;
                const float mp = (ww >= 0 && ww < NW) ? mrow[r + ky][ww] : 0.f;
                const float g = mp - mc;
                const float val = 1.0f / (g * g + EPSV);
                v[ky * 3 + kx + 1] = val;
                vmax = fmaxf(vmax, val);
            }
        }
        float sum = 0.f;
        #pragma unroll
        for (int k = 0; k < 9; ++k) { v[k] = __expf(v[k] - vmax); sum += v[k]; }
        const float rs = 1.0f / sum;
        #pragma unroll
        for (int k = 0; k < 9; ++k) wgt[r][k][w] = v[k] * rs;
    }
    __syncthreads();

    // ---------------- Phase C: reassembly ----------------
    const int wp = tid & 63;                     // source cols 2wp, 2wp+1
    const int cg_ = tid >> 6;                    // 0..15 -> 8 channels each
    const int wa = 2 * wp;

    float wA0[9], wB0[9], wA1[9], wB1[9];
    #pragma unroll
    for (int k = 0; k < 9; ++k) {
        wA0[k] = wgt[0][k][wa];  wB0[k] = wgt[0][k][wa + 1];
        wA1[k] = wgt[1][k][wa];  wB1[k] = wgt[1][k][wa + 1];
    }

    const bool rv0 = (h0 > 0), rv3 = (h0 + 2 < NH);
    const bool tv0 = (wp > 0), tv3 = (wp < 63);

    #pragma unroll 2
    for (int i = 0; i < 8; ++i) {
        const int c = cg_ * 8 + i;
        const float* xc = x + ((size_t)(b * NC + c)) * (NH * NW);

        float a[4][4];                           // rows h0-1..h0+2, taps wa-1..wa+2
        #pragma unroll
        for (int rr = 0; rr < 4; ++rr) {
            const int hh = h0 - 1 + rr;
            const bool rv = (rr == 0) ? rv0 : ((rr == 3) ? rv3 : true);
            const float* row = xc + hh * NW + wa;
            const v2f m = rv ? *(const v2f*)row : (v2f){0.f, 0.f};
            a[rr][0] = (rv && tv0) ? row[-1] : 0.f;
            a[rr][1] = m.x;
            a[rr][2] = m.y;
            a[rr][3] = (rv && tv3) ? row[2] : 0.f;
        }

        float v0a = 0.f, v0b = 0.f, v1a = 0.f, v1b = 0.f;
        #pragma unroll
        for (int ky = 0; ky < 3; ++ky) {
            #pragma unroll
            for (int kx = 0; kx < 3; ++kx) {
                const int k = ky * 3 + kx;
                v0a += wA0[k] * a[ky][kx];
                v0b += wB0[k] * a[ky][kx + 1];
                v1a += wA1[k] * a[ky + 1][kx];
                v1b += wB1[k] * a[ky + 1][kx + 1];
            }
        }

        float* o = out + ((size_t)(b * NC + c) * (NH * 2) + 2 * h0) * (NW * 2) + 4 * wp;
        const v4f p0 = {v0a, v0a, v0b, v0b};
        const v4f p1 = {v1a, v1a, v1b, v1b};
        __builtin_nontemporal_store(p0, (v4f*)(o));
        __builtin_nontemporal_store(p0, (v4f*)(o + (NW * 2)));
        __builtin_nontemporal_store(p1, (v4f*)(o + 2 * (NW * 2)));
        __builtin_nontemporal_store(p1, (v4f*)(o + 3 * (NW * 2)));
    }
}

extern "C" void kernel_launch(void* const* d_in, const int* in_sizes, int n_in,
                              void* d_out, int out_size, void* d_ws, size_t ws_size,
                              hipStream_t stream) {
    const float* x = (const float*)d_in[0];
    float* out = (float*)d_out;
    fused_carafe<<<dim3(NB * NH / TH), dim3(1024), 0, stream>>>(x, out);
}